// Round 18
// baseline (215.338 us; speedup 1.0000x reference)
//
#include <hip/hip_runtime.h>
#include <stdint.h>

// Problem constants
#define BB 256
#define NNODE 12
#define PP 66
#define DNF 1024
#define DEF 1024
#define DD 512
#define MROWS (BB*PP)        // 16896
#define MNODE (BB*NNODE)     // 3072
#define MTILES (MROWS/128)   // 132

typedef __attribute__((ext_vector_type(8))) short s16x8;
typedef __attribute__((ext_vector_type(4))) float f32x4;
typedef __attribute__((ext_vector_type(8))) unsigned short u16x8;

__device__ __forceinline__ unsigned short f2bf(float f) {
  union { float f; unsigned u; } v; v.f = f;
  return (unsigned short)((v.u + 0x7FFFu + ((v.u >> 16) & 1u)) >> 16);
}
__device__ __forceinline__ float bf2f(unsigned short h) {
  union { unsigned u; float f; } v; v.u = ((unsigned)h) << 16;
  return v.f;
}

__device__ __forceinline__ void gll16(const void* g, void* l) {
  __builtin_amdgcn_global_load_lds(
      (const __attribute__((address_space(1))) void*)g,
      (__attribute__((address_space(3))) void*)l, 16, 0, 0);
}

// ---------------- k_front: h1c partials + scan + prep (ONE launch) ----------
// [0,24) h1c partials ; [24] scan ; [25,3097) conv ; [3097,4889) transposes ;
// [4889,5657) W2 block-diag pack [128][1536] ; [5657,5669) b0cat ;
// [5669,5675) b1cat ; [5675,5679) b_ne
__global__ __launch_bounds__(256) void k_front(
    const int* __restrict__ nrels, int* __restrict__ offs,
    int* __restrict__ Mv, int2* __restrict__ nodes,
    float* __restrict__ h1part,
    const float* __restrict__ node, unsigned short* __restrict__ node_bf,
    const float* __restrict__ W_node, unsigned short* __restrict__ WnT,
    const float* __restrict__ W_edge, unsigned short* __restrict__ WeT,
    const float* __restrict__ W0a, const float* __restrict__ W0b,
    const float* __restrict__ W0c, unsigned short* __restrict__ W0T,
    const float* __restrict__ W1a, const float* __restrict__ W1b,
    const float* __restrict__ W1c, unsigned short* __restrict__ W1T,
    const float* __restrict__ w2a, const float* __restrict__ w2b,
    const float* __restrict__ w2c,
    const float* __restrict__ b2a, const float* __restrict__ b2b,
    const float* __restrict__ b2c,
    unsigned short* __restrict__ W2T, float* __restrict__ b2pad,
    const float* __restrict__ b0a, const float* __restrict__ b0b,
    const float* __restrict__ b0c, float* __restrict__ b0cat,
    const float* __restrict__ b1a, const float* __restrict__ b1b,
    const float* __restrict__ b1c, float* __restrict__ b1cat,
    const float* __restrict__ b_node, const float* __restrict__ b_edge,
    float* __restrict__ b_ne) {
  __shared__ float tile[64][65];
  const int bid = blockIdx.x, t = threadIdx.x;
  if (bid < 24) {
    const int h = bid >> 3, c = bid & 7;
    const float* b0 = h == 0 ? b0a : (h == 1 ? b0b : b0c);
    const float* W1 = h == 0 ? W1a : (h == 1 ? W1b : W1c);
    const int k0 = c * 128;
    float acc0 = 0.f, acc1 = 0.f;
#pragma unroll 8
    for (int kk = 0; kk < 128; ++kk) {
      const int k = k0 + kk;
      const float bv = fmaxf(b0[k], 0.f);
      acc0 += bv * W1[(size_t)k * 512 + t];
      acc1 += bv * W1[(size_t)k * 512 + t + 256];
    }
    h1part[(size_t)bid * 512 + t] = acc0;
    h1part[(size_t)bid * 512 + t + 256] = acc1;
  } else if (bid == 24) {
    __shared__ int s[256];
    const int val = nrels[t];
    s[t] = val;
    __syncthreads();
    for (int d = 1; d < 256; d <<= 1) {
      int x = (t >= d) ? s[t - d] : 0;
      __syncthreads();
      s[t] += x;
      __syncthreads();
    }
    offs[t] = s[t] - val;
    __syncthreads();
    const int total = s[255];
    if (t == 0) *Mv = total;
    if (t < 128) {
      int cr = total + t;
      if (cr < MROWS) nodes[cr] = make_int2(0, 0);
    }
  } else if (bid < 3097) {
    int i = (bid - 25) * 256 + t;
    float4 v = ((const float4*)node)[i];
    ushort4 o;
    o.x = f2bf(v.x); o.y = f2bf(v.y); o.z = f2bf(v.z); o.w = f2bf(v.w);
    ((ushort4*)node_bf)[i] = o;
  } else if (bid < 4889) {
    int tau = bid - 3097;
    const float* src; unsigned short* dst; int K, N;
    if (tau < 128)       { src = W_node; dst = WnT; K = 1024; N = 512; }
    else if (tau < 256)  { src = W_edge; dst = WeT; K = 1024; N = 512; tau -= 128; }
    else if (tau < 1408) {
      int hh = (tau - 256) / 384; tau = (tau - 256) % 384;
      src = hh == 0 ? W0a : (hh == 1 ? W0b : W0c);
      dst = W0T + (size_t)hh * 1024 * 1536; K = 1536; N = 1024;
    } else {
      int hh = (tau - 1408) / 128; tau = (tau - 1408) % 128;
      src = hh == 0 ? W1a : (hh == 1 ? W1b : W1c);
      dst = W1T + (size_t)hh * 512 * 1024; K = 1024; N = 512;
    }
    const int ntn = N >> 6;
    const int kb = (tau / ntn) * 64, nb = (tau % ntn) * 64;
    const int tx = t & 15, ty = t >> 4;
#pragma unroll
    for (int i = 0; i < 4; i++) {
      float4 v = *(const float4*)&src[(size_t)(kb + ty + 16 * i) * N + nb + tx * 4];
      tile[ty + 16 * i][tx * 4 + 0] = v.x;
      tile[ty + 16 * i][tx * 4 + 1] = v.y;
      tile[ty + 16 * i][tx * 4 + 2] = v.z;
      tile[ty + 16 * i][tx * 4 + 3] = v.w;
    }
    __syncthreads();
    const int wx = t & 7, wy = t >> 3;
#pragma unroll
    for (int i = 0; i < 2; i++) {
      const int n = wy + 32 * i;
      u16x8 o;
#pragma unroll
      for (int j = 0; j < 8; j++) o[j] = f2bf(tile[wx * 8 + j][n]);
      *(u16x8*)&dst[(size_t)(nb + n) * K + kb + wx * 8] = o;
    }
  } else if (bid < 5657) {
    // W2 block-diagonal pack: W2T [128 rows (classes)][1536 K], row c nonzero
    // only in its head's 512-wide K block. 196608 elems / 256 = 768 blocks.
    const int blk = bid - 4889;
    const int idx = blk * 256 + t;           // < 196608
    const int n = idx / 1536, k = idx - n * 1536;
    unsigned short v = 0;
    if (n < 9) {
      if (k < 512) v = f2bf(w2a[(size_t)k * 9 + n]);
    } else if (n < 12) {
      if (k >= 512 && k < 1024) v = f2bf(w2b[(size_t)(k - 512) * 3 + (n - 9)]);
    } else if (n < 17) {
      if (k >= 1024) v = f2bf(w2c[(size_t)(k - 1024) * 5 + (n - 12)]);
    }
    W2T[idx] = v;
    if (blk == 0 && t < 128) {
      float bv = 0.f;
      if (t < 9) bv = b2a[t];
      else if (t < 12) bv = b2b[t - 9];
      else if (t < 17) bv = b2c[t - 12];
      b2pad[t] = bv;
    }
  } else if (bid < 5669) {
    int j = bid - 5657;
    const float* b0 = (j < 4) ? b0a : (j < 8 ? b0b : b0c);
    b0cat[j * 256 + t] = b0[(j & 3) * 256 + t];
  } else if (bid < 5675) {
    int j = bid - 5669;
    const float* b1 = (j < 2) ? b1a : (j < 4 ? b1b : b1c);
    b1cat[j * 256 + t] = b1[(j & 1) * 256 + t];
  } else {
    int idx = (bid - 5675) * 256 + t;
    b_ne[idx] = (idx < 512) ? b_node[idx] : b_edge[idx - 512];
  }
}

// ---------------- shared GEMM body (m97-family, EXACTLY 32 KB LDS) ----------
// EPI: 0 = +bias -> bf16 ; 1 = e-assembly into ci_e (compact) ;
//      2 = relu(+bias) -> bf16 ; 3 = merged block-diag layer-2: cols<17
//          decode head, scatter fp32 via rmap ; 4 = raw bf16 ;
//      5 = L0': relu(bias + acc + npair), chunk-XOR LDS stage.
template <int EPI>
__device__ __forceinline__ void gemm_body(
    unsigned short* sm,
    const unsigned short* __restrict__ A, int ldA,
    const unsigned short* __restrict__ BT, int ldB, int K,
    int Ntiles,
    const float* __restrict__ bias,
    unsigned short* __restrict__ outb, int ldo,
    const unsigned short* __restrict__ em,
    const int* __restrict__ Mvp,
    unsigned short* __restrict__ ci,
    int blocksPerHead, long long aHeadOff, long long bHeadOff,
    long long oHeadOff, int biasHeadOff,
    const int2* __restrict__ nodes,
    const unsigned short* __restrict__ nfa,
    const unsigned short* __restrict__ nfb,
    const int* __restrict__ rmap, int bid) {
  char* smc = (char*)sm;
  const int t = threadIdx.x;
  const int l = t & 63, w = t >> 6;
  const int wm = w >> 1, wn = w & 1;

  int head = 0;
  unsigned short* outp = outb;
  if (blocksPerHead > 0) {
    head = bid / blocksPerHead;
    bid -= head * blocksPerHead;
    A += (long long)head * aHeadOff;
    BT += (long long)head * bHeadOff;
    bias += head * biasHeadOff;
    outp = outb + (long long)head * oHeadOff;
  }
  const int tn = bid % Ntiles, tm = bid / Ntiles;

  int Mv = MROWS;
  if (Mvp) {
    Mv = *Mvp;
    if (tm * 128 >= Mv) return;   // compact early-exit (uniform branch)
  }

  const int lrow = l >> 3;
  const int scol = (l & 7) ^ lrow;       // pre-swizzled source chunk
  const unsigned short* Ap = A + (size_t)(tm * 128 + w * 8 + lrow) * ldA + scol * 8;
  const unsigned short* Bp = BT + (size_t)(tn * 128 + w * 8 + lrow) * ldB + scol * 8;

  f32x4 acc[4][4] = {};
  const int hi = l >> 4, l15 = l & 15, l7 = l & 7;
  const int nk = K >> 6;

  for (int kt = 0; kt < nk; ++kt) {
#pragma unroll
    for (int c = 0; c < 4; ++c) {
      gll16(Ap + (size_t)c * 32 * ldA, smc + c * 4096 + w * 1024);
      gll16(Bp + (size_t)c * 32 * ldB, smc + 16384 + c * 4096 + w * 1024);
    }
    __syncthreads();
#pragma unroll
    for (int kk = 0; kk < 2; ++kk) {
      const int cb = (((kk << 2) + hi) ^ l7) << 4;
      s16x8 af[4], bfr[4];
#pragma unroll
      for (int m = 0; m < 4; m++)
        af[m] = *(const s16x8*)(smc + (wm * 64 + m * 16 + l15) * 128 + cb);
#pragma unroll
      for (int n = 0; n < 4; n++)
        bfr[n] = *(const s16x8*)(smc + 16384 + (wn * 64 + n * 16 + l15) * 128 + cb);
#pragma unroll
      for (int m = 0; m < 4; m++)
#pragma unroll
        for (int n = 0; n < 4; n++)
          asm volatile("v_mfma_f32_16x16x32_bf16 %0, %1, %2, %0"
                       : "+v"(acc[m][n])
                       : "v"(af[m]), "v"(bfr[n]));
    }
    __syncthreads();
    Ap += 64;
    Bp += 64;
  }
  asm volatile("s_nop 7\n\ts_nop 7\n\ts_nop 7" :::);  // MFMA->VALU hazard guard

  if constexpr (EPI == 5) {
    // Stage npair = nfa[i0]+nfb[i1], coalesced 16B/lane; chunk-XOR swizzle.
    const int se_r = t >> 4;
    const int se_ch = t & 15;
#pragma unroll
    for (int it = 0; it < 8; ++it) {
      const int rr = se_r + (it << 4);
      const int2 nn = nodes[tm * 128 + rr];   // pad rows zero-initialized
      union { unsigned short s[8]; unsigned long long q[2]; } ov;
      u16x8 va = *(const u16x8*)&nfa[(size_t)nn.x * 3072 + tn * 128 + se_ch * 8];
      u16x8 vb = *(const u16x8*)&nfb[(size_t)nn.y * 3072 + tn * 128 + se_ch * 8];
#pragma unroll
      for (int j = 0; j < 8; ++j)
        ov.s[j] = f2bf(bf2f(va[j]) + bf2f(vb[j]));
      const int sch = se_ch ^ ((rr >> 2) & 7);
      *(unsigned long long*)(smc + rr * 256 + (sch << 4)) = ov.q[0];
      *(unsigned long long*)(smc + rr * 256 + (sch << 4) + 8) = ov.q[1];
    }
    __syncthreads();
  }

  // C/D layout: col = lane&15, row = (lane>>4)*4 + reg
  const int gr_base = tm * 128 + wm * 64 + (hi << 2);
  const int gc_base = tn * 128 + wn * 64 + l15;
  const int lr_base = wm * 64 + (hi << 2);
  const int lc_base = wn * 64 + l15;

#pragma unroll
  for (int n = 0; n < 4; n++) {
    const int gc = gc_base + n * 16;
    const float bv = (EPI == 4) ? 0.f : bias[gc];
#pragma unroll
    for (int m = 0; m < 4; m++) {
#pragma unroll
      for (int i = 0; i < 4; i++) {
        const int gr = gr_base + m * 16 + i;
        float v = acc[m][n][i] + bv;
        if constexpr (EPI == 0 || EPI == 4) {
          outp[(size_t)gr * ldo + gc] = f2bf(v);
        } else if constexpr (EPI == 1) {
          float e = bf2f(em[(size_t)gr * DD + gc]) + 0.5f * v;
          ci[(size_t)gr * DD + gc] = f2bf(e);
        } else if constexpr (EPI == 2) {
          outp[(size_t)gr * ldo + gc] = f2bf(v > 0.f ? v : 0.f);
        } else if constexpr (EPI == 5) {
          const int lr = lr_base + m * 16 + i;
          const int lc = lc_base + n * 16;
          const int rch = (lc >> 3) ^ ((lr >> 2) & 7);
          v += bf2f(*(const unsigned short*)(smc + lr * 256 + (rch << 4) + (lc & 7) * 2));
          outp[(size_t)gr * ldo + gc] = f2bf(v > 0.f ? v : 0.f);
        } else {
          // EPI 3: merged block-diag layer-2 scatter (h1cat K=1536 input)
          if (gc < 17 && gr < Mv) {
            const int hh = gc < 9 ? 0 : (gc < 12 ? 1 : 2);
            const int Ch = hh == 0 ? 9 : (hh == 1 ? 3 : 5);
            const int cc = gc - (hh == 0 ? 0 : (hh == 1 ? 9 : 12));
            const size_t ob = hh == 0 ? 0
                             : (hh == 1 ? (size_t)MROWS * 9 : (size_t)MROWS * 12);
            ((float*)outb)[ob + (size_t)rmap[gr] * Ch + cc] = v;
          }
        }
      }
    }
  }
}

// ---- k_gather_nf: compact gather + outc finish + nf GEMM (ONE launch) ------
__global__ __launch_bounds__(256) void k_gather_nf(
    const float* __restrict__ EF, const float* __restrict__ EE,
    const int* __restrict__ pairs, const int* __restrict__ nrels,
    const int* __restrict__ offs,
    unsigned short* __restrict__ efm, unsigned short* __restrict__ emb,
    int2* __restrict__ nodes, int* __restrict__ rmap,
    const float* __restrict__ h1part,
    const float* __restrict__ b1a, const float* __restrict__ b1b,
    const float* __restrict__ b1c,
    const float* __restrict__ w2a, const float* __restrict__ w2b,
    const float* __restrict__ w2c,
    const float* __restrict__ b2a, const float* __restrict__ b2b,
    const float* __restrict__ b2c, float* __restrict__ outc,
    const unsigned short* __restrict__ node_bf,
    const unsigned short* __restrict__ WnT,
    const float* __restrict__ b_node, unsigned short* __restrict__ nf) {
  __shared__ __align__(16) unsigned short sm[16384];
  const int bid = blockIdx.x, t = threadIdx.x;
  if (bid > MROWS) {
    gemm_body<0>(sm, node_bf, 1024, WnT, 1024, 1024, 4, b_node, nf, 512,
                 nullptr, nullptr, nullptr, 0, 0, 0, 0, 0,
                 nullptr, nullptr, nullptr, nullptr, bid - MROWS - 1);
    return;
  }
  if (bid == MROWS) {
    float* red = (float*)sm;
    for (int h = 0; h < 3; ++h) {
      const float* b1 = h == 0 ? b1a : (h == 1 ? b1b : b1c);
      const float* W2 = h == 0 ? w2a : (h == 1 ? w2b : w2c);
      const float* b2 = h == 0 ? b2a : (h == 1 ? b2b : b2c);
      const int C = h == 0 ? 9 : (h == 1 ? 3 : 5);
      const int obase = h == 0 ? 0 : (h == 1 ? 9 : 12);
      if (t < 9) red[t] = 0.f;
      float s0 = b1[t], s1 = b1[t + 256];
#pragma unroll
      for (int cc = 0; cc < 8; ++cc) {
        s0 += h1part[(size_t)(h * 8 + cc) * 512 + t];
        s1 += h1part[(size_t)(h * 8 + cc) * 512 + t + 256];
      }
      const float hv0 = fmaxf(s0, 0.f), hv1 = fmaxf(s1, 0.f);
      __syncthreads();
      float p[9] = {0.f, 0.f, 0.f, 0.f, 0.f, 0.f, 0.f, 0.f, 0.f};
#pragma unroll
      for (int c = 0; c < 9; ++c)
        if (c < C) p[c] = hv0 * W2[(size_t)t * C + c] + hv1 * W2[(size_t)(t + 256) * C + c];
#pragma unroll
      for (int c = 0; c < 9; ++c)
#pragma unroll
        for (int off = 32; off; off >>= 1) p[c] += __shfl_xor(p[c], off);
      if ((t & 63) == 0)
        for (int c = 0; c < C; ++c) atomicAdd(&red[c], p[c]);
      __syncthreads();
      if (t < C) outc[obase + t] = red[t] + b2[t];
      __syncthreads();
    }
    return;
  }
  int r = bid;
  int b = r / PP, p = r - b * PP;
  if (p >= nrels[b]) return;
  const int cr = offs[b] + p;
  int i0 = pairs[r * 2 + 0], i1 = pairs[r * 2 + 1];
  if (t == 0) {
    nodes[cr] = make_int2(b * NNODE + i0, b * NNODE + i1);
    rmap[cr] = r;
  }
  const float4* e01 = (const float4*)(EF + ((size_t)((b * NNODE + i0) * NNODE + i1)) * DEF);
  const float4* e10 = (const float4*)(EF + ((size_t)((b * NNODE + i1) * NNODE + i0)) * DEF);
  float4 a = e01[t], c = e10[t];
  ushort4 o;
  o.x = f2bf(0.5f * (a.x + c.x));
  o.y = f2bf(0.5f * (a.y + c.y));
  o.z = f2bf(0.5f * (a.z + c.z));
  o.w = f2bf(0.5f * (a.w + c.w));
  ((ushort4*)(efm + (size_t)cr * DEF))[t] = o;
  const float2* g01 = (const float2*)(EE + ((size_t)((b * NNODE + i0) * NNODE + i1)) * DD);
  const float2* g10 = (const float2*)(EE + ((size_t)((b * NNODE + i1) * NNODE + i0)) * DD);
  float2 x = g01[t], y = g10[t];
  ushort2 eo;
  eo.x = f2bf(0.25f * (x.x + y.x));
  eo.y = f2bf(0.25f * (x.y + y.y));
  ((ushort2*)(emb + (size_t)cr * DD))[t] = eo;
}

// ---- k_mid: e-GEMM + nfa/nfb GEMM (ONE launch; fillout in k_l0) -------------
__global__ __launch_bounds__(256) void k_mid(
    const unsigned short* __restrict__ efm, const unsigned short* __restrict__ WeT,
    const float* __restrict__ b_edge,
    const unsigned short* __restrict__ EMb, const int* __restrict__ Mvp,
    unsigned short* __restrict__ ci_e,
    const unsigned short* __restrict__ nf, const unsigned short* __restrict__ W0T,
    unsigned short* __restrict__ nfa) {
  __shared__ __align__(16) unsigned short sm[16384];
  const int bid = blockIdx.x;
  if (bid < 528) {
    gemm_body<1>(sm, efm, 1024, WeT, 1024, 1024, 4, b_edge, nullptr, 0,
                 EMb, Mvp, ci_e, 0, 0, 0, 0, 0,
                 nullptr, nullptr, nullptr, nullptr, bid);
  } else {
    gemm_body<4>(sm, nf, 512, W0T, 1536, 512, 24, nullptr, nfa, 3072,
                 nullptr, nullptr, nullptr, 576,
                 0, 512, (long long)MNODE * 3072, 0,
                 nullptr, nullptr, nullptr, nullptr, bid - 528);
  }
}

// ---- k_l0: fillout riders + L0' GEMM (ONE launch) ---------------------------
__global__ __launch_bounds__(256) void k_l0(
    const unsigned short* __restrict__ ci_e,
    const unsigned short* __restrict__ W0Te,   // W0T + 1024 (e-part rows)
    const float* __restrict__ b0cat,
    unsigned short* __restrict__ h0big,
    const int* __restrict__ Mvp, const int2* __restrict__ nodes,
    const unsigned short* __restrict__ nfa,
    const unsigned short* __restrict__ nfb,
    const float* __restrict__ outc, float* __restrict__ out) {
  __shared__ __align__(16) unsigned short sm[16384];
  const int bid = blockIdx.x, t = threadIdx.x;
  if (bid < 1122) {
    const int e = bid * 256 + t;
    if (e < MROWS * 17) {
      int c;
      if (e < MROWS * 9) c = e % 9;
      else if (e < MROWS * 12) c = 9 + (e - MROWS * 9) % 3;
      else c = 12 + (e - MROWS * 12) % 5;
      out[e] = outc[c];
    }
    return;
  }
  gemm_body<5>(sm, ci_e, 512, W0Te, 1536, 512, 24, b0cat, h0big, 3072,
               nullptr, Mvp, nullptr, 0, 0, 0, 0, 0,
               nodes, nfa, nfb, nullptr, bid - 1122);
}

// ---------------- plain GEMM wrapper (L1, L2) --------------------------------
template <int EPI>
__global__ __launch_bounds__(256) void k_gemm(
    const unsigned short* __restrict__ A, int ldA,
    const unsigned short* __restrict__ BT, int ldB, int K,
    int Ntiles,
    const float* __restrict__ bias,
    unsigned short* __restrict__ outb, int ldo,
    const unsigned short* __restrict__ em,
    const int* __restrict__ Mvp,
    unsigned short* __restrict__ ci,
    int blocksPerHead, long long aHeadOff, long long bHeadOff,
    long long oHeadOff, int biasHeadOff,
    const int2* __restrict__ nodes,
    const unsigned short* __restrict__ nfa,
    const unsigned short* __restrict__ nfb,
    const int* __restrict__ rmap) {
  __shared__ __align__(16) unsigned short sm[16384];
  gemm_body<EPI>(sm, A, ldA, BT, ldB, K, Ntiles, bias, outb, ldo, em, Mvp, ci,
                 blocksPerHead, aHeadOff, bHeadOff, oHeadOff, biasHeadOff,
                 nodes, nfa, nfb, rmap, blockIdx.x);
}

// ---------------- launcher ----------------
extern "C" void kernel_launch(void* const* d_in, const int* in_sizes, int n_in,
                              void* d_out, int out_size, void* d_ws, size_t ws_size,
                              hipStream_t stream) {
  const float* node   = (const float*)d_in[0];
  const float* EF     = (const float*)d_in[1];
  const float* EE     = (const float*)d_in[2];
  const int*   pairs  = (const int*)d_in[3];
  const int*   nrels  = (const int*)d_in[4];
  const float* W_node = (const float*)d_in[5];
  const float* b_node = (const float*)d_in[6];
  const float* W_edge = (const float*)d_in[7];
  const float* b_edge = (const float*)d_in[8];
  const float* hW0[3] = {(const float*)d_in[9],  (const float*)d_in[15], (const float*)d_in[21]};
  const float* hb0[3] = {(const float*)d_in[10], (const float*)d_in[16], (const float*)d_in[22]};
  const float* hW1[3] = {(const float*)d_in[11], (const float*)d_in[17], (const float*)d_in[23]};
  const float* hb1[3] = {(const float*)d_in[12], (const float*)d_in[18], (const float*)d_in[24]};
  const float* hW2[3] = {(const float*)d_in[13], (const float*)d_in[19], (const float*)d_in[25]};
  const float* hb2[3] = {(const float*)d_in[14], (const float*)d_in[20], (const float*)d_in[26]};

  char* ws = (char*)d_ws;
  size_t off = 0;
  auto alloc = [&](size_t bytes) {
    char* p = ws + off;
    off += (bytes + 255) & ~(size_t)255;
    return p;
  };
  // --- persistent front ---
  unsigned short* WnT    = (unsigned short*)alloc((size_t)512 * 1024 * 2);
  unsigned short* WeT    = (unsigned short*)alloc((size_t)512 * 1024 * 2);
  unsigned short* W0T    = (unsigned short*)alloc((size_t)3072 * 1536 * 2);
  unsigned short* W1T    = (unsigned short*)alloc((size_t)3 * 512 * 1024 * 2);
  unsigned short* W2T    = (unsigned short*)alloc((size_t)128 * 1536 * 2);  // block-diag
  float*          b2pad  = (float*)alloc((size_t)128 * 4);
  float*          b0cat  = (float*)alloc((size_t)3072 * 4);
  float*          b1cat  = (float*)alloc((size_t)1536 * 4);
  float*          b_ne   = (float*)alloc((size_t)1024 * 4);
  int2*           nodes  = (int2*)alloc((size_t)MROWS * 8);
  int*            offs   = (int*)alloc((size_t)256 * 4);
  int*            Mv     = (int*)alloc(256);
  int*            rmap   = (int*)alloc((size_t)MROWS * 4);
  float*          outc   = (float*)alloc((size_t)32 * 4);
  float*          h1part = (float*)alloc((size_t)24 * 512 * 4);
  // --- zone B: [ci_e | nfa | nfb] (55.1 MB), disjoint from efm/EMb.
  //     Dead after L0' -> h1cat [MROWS][1536] (51.9 MB) overlays zone B.
  size_t zoneB = off;
  unsigned short* ci_e = (unsigned short*)alloc((size_t)MROWS * DD * 2);
  unsigned short* nfa  = (unsigned short*)alloc((size_t)MNODE * 3072 * 2);
  unsigned short* nfb  = (unsigned short*)alloc((size_t)MNODE * 3072 * 2);
  // --- zone C: [node_bf | nf | efm | EMb], dead after k_mid -> h0big overlays.
  size_t zoneC = off;
  unsigned short* node_bf = (unsigned short*)alloc((size_t)MNODE * DNF * 2);
  unsigned short* nf      = (unsigned short*)alloc((size_t)MNODE * DD * 2);
  unsigned short* efm     = (unsigned short*)alloc((size_t)MROWS * DEF * 2);
  unsigned short* EMb     = (unsigned short*)alloc((size_t)MROWS * DD * 2);
  // overlays
  unsigned short* h1    = (unsigned short*)(ws + zoneB);   // h1cat [MROWS][1536]
  unsigned short* h0big = (unsigned short*)(ws + zoneC);

  // 1. front: h1c partials + scan + conv + transposes + W2 block-diag + pads
  k_front<<<5679, 256, 0, stream>>>(nrels, offs, Mv, nodes, h1part,
      node, node_bf, W_node, WnT, W_edge, WeT,
      hW0[0], hW0[1], hW0[2], W0T, hW1[0], hW1[1], hW1[2], W1T,
      hW2[0], hW2[1], hW2[2], hb2[0], hb2[1], hb2[2], W2T, b2pad,
      hb0[0], hb0[1], hb0[2], b0cat, hb1[0], hb1[1], hb1[2], b1cat,
      b_node, b_edge, b_ne);

  // 2. gather + finish + nf GEMM
  k_gather_nf<<<MROWS + 1 + (MNODE / 128) * 4, 256, 0, stream>>>(
      EF, EE, pairs, nrels, offs, efm, EMb, nodes, rmap, h1part,
      hb1[0], hb1[1], hb1[2], hW2[0], hW2[1], hW2[2],
      hb2[0], hb2[1], hb2[2], outc,
      node_bf, WnT, b_ne, nf);

  // 3. mid: e-GEMM + nfa/nfb
  k_mid<<<1680, 256, 0, stream>>>(
      efm, WeT, b_ne + 512, EMb, Mv, ci_e, nf, W0T, nfa);

  // 4. L0' + fillout riders
  k_l0<<<1122 + MTILES * 24, 256, 0, stream>>>(
      ci_e, W0T + 1024, b0cat, h0big, Mv, nodes, nfa, nfb,
      outc, (float*)d_out);

  // 5. L1 (compact, fused over heads) -> h1cat[r][h*512+n]  (ldo=1536)
  k_gemm<2><<<3 * MTILES * 4, 256, 0, stream>>>(
      h0big, 3072, W1T, 1024, 1024, 4, b1cat, h1, 1536,
      nullptr, Mv, nullptr, MTILES * 4,
      1024, (long long)512 * 1024, 512, 512,
      nullptr, nullptr, nullptr, nullptr);

  // 6. L2 (merged block-diag): h1cat [Mv][1536] x W2T [128][1536]^T, K=1536;
  //    EPI3 decodes head per column and scatters into pre-filled d_out.
  k_gemm<3><<<MTILES, 256, 0, stream>>>(
      h1, 1536, W2T, 1536, 1536, 1, b2pad, (unsigned short*)d_out, 0,
      nullptr, Mv, nullptr, 0, 0, 0, 0, 0, nullptr, nullptr, nullptr, rmap);
}

// Round 20
// 198.876 us; speedup vs baseline: 1.0828x; 1.0828x over previous
//
#include <hip/hip_runtime.h>
#include <stdint.h>

// Problem constants
#define BB 256
#define NNODE 12
#define PP 66
#define DNF 1024
#define DEF 1024
#define DD 512
#define MROWS (BB*PP)        // 16896
#define MNODE (BB*NNODE)     // 3072
#define MTILES (MROWS/128)   // 132

typedef __attribute__((ext_vector_type(8))) short s16x8;
typedef __attribute__((ext_vector_type(4))) float f32x4;
typedef __attribute__((ext_vector_type(8))) unsigned short u16x8;

__device__ __forceinline__ unsigned short f2bf(float f) {
  union { float f; unsigned u; } v; v.f = f;
  return (unsigned short)((v.u + 0x7FFFu + ((v.u >> 16) & 1u)) >> 16);
}
__device__ __forceinline__ float bf2f(unsigned short h) {
  union { unsigned u; float f; } v; v.u = ((unsigned)h) << 16;
  return v.f;
}

__device__ __forceinline__ void gll16(const void* g, void* l) {
  __builtin_amdgcn_global_load_lds(
      (const __attribute__((address_space(1))) void*)g,
      (__attribute__((address_space(3))) void*)l, 16, 0, 0);
}

// ---------------- k_front: h1c partials + scan + prep (ONE launch) ----------
__global__ __launch_bounds__(256) void k_front(
    const int* __restrict__ nrels, int* __restrict__ offs,
    int* __restrict__ Mv, int2* __restrict__ nodes,
    float* __restrict__ h1part,
    const float* __restrict__ node, unsigned short* __restrict__ node_bf,
    const float* __restrict__ W_node, unsigned short* __restrict__ WnT,
    const float* __restrict__ W_edge, unsigned short* __restrict__ WeT,
    const float* __restrict__ W0a, const float* __restrict__ W0b,
    const float* __restrict__ W0c, unsigned short* __restrict__ W0T,
    const float* __restrict__ W1a, const float* __restrict__ W1b,
    const float* __restrict__ W1c, unsigned short* __restrict__ W1T,
    const float* __restrict__ w2a, const float* __restrict__ w2b,
    const float* __restrict__ w2c,
    const float* __restrict__ b2a, const float* __restrict__ b2b,
    const float* __restrict__ b2c,
    unsigned short* __restrict__ W2T, float* __restrict__ b2pad,
    const float* __restrict__ b0a, const float* __restrict__ b0b,
    const float* __restrict__ b0c, float* __restrict__ b0cat,
    const float* __restrict__ b1a, const float* __restrict__ b1b,
    const float* __restrict__ b1c, float* __restrict__ b1cat,
    const float* __restrict__ b_node, const float* __restrict__ b_edge,
    float* __restrict__ b_ne) {
  __shared__ float tile[64][65];
  const int bid = blockIdx.x, t = threadIdx.x;
  if (bid < 24) {
    const int h = bid >> 3, c = bid & 7;
    const float* b0 = h == 0 ? b0a : (h == 1 ? b0b : b0c);
    const float* W1 = h == 0 ? W1a : (h == 1 ? W1b : W1c);
    const int k0 = c * 128;
    float acc0 = 0.f, acc1 = 0.f;
#pragma unroll 8
    for (int kk = 0; kk < 128; ++kk) {
      const int k = k0 + kk;
      const float bv = fmaxf(b0[k], 0.f);
      acc0 += bv * W1[(size_t)k * 512 + t];
      acc1 += bv * W1[(size_t)k * 512 + t + 256];
    }
    h1part[(size_t)bid * 512 + t] = acc0;
    h1part[(size_t)bid * 512 + t + 256] = acc1;
  } else if (bid == 24) {
    __shared__ int s[256];
    const int val = nrels[t];
    s[t] = val;
    __syncthreads();
    for (int d = 1; d < 256; d <<= 1) {
      int x = (t >= d) ? s[t - d] : 0;
      __syncthreads();
      s[t] += x;
      __syncthreads();
    }
    offs[t] = s[t] - val;
    __syncthreads();
    const int total = s[255];
    if (t == 0) *Mv = total;
    if (t < 128) {
      int cr = total + t;
      if (cr < MROWS) nodes[cr] = make_int2(0, 0);
    }
  } else if (bid < 3097) {
    int i = (bid - 25) * 256 + t;
    float4 v = ((const float4*)node)[i];
    ushort4 o;
    o.x = f2bf(v.x); o.y = f2bf(v.y); o.z = f2bf(v.z); o.w = f2bf(v.w);
    ((ushort4*)node_bf)[i] = o;
  } else if (bid < 4889) {
    int tau = bid - 3097;
    const float* src; unsigned short* dst; int K, N;
    if (tau < 128)       { src = W_node; dst = WnT; K = 1024; N = 512; }
    else if (tau < 256)  { src = W_edge; dst = WeT; K = 1024; N = 512; tau -= 128; }
    else if (tau < 1408) {
      int hh = (tau - 256) / 384; tau = (tau - 256) % 384;
      src = hh == 0 ? W0a : (hh == 1 ? W0b : W0c);
      dst = W0T + (size_t)hh * 1024 * 1536; K = 1536; N = 1024;
    } else {
      int hh = (tau - 1408) / 128; tau = (tau - 1408) % 128;
      src = hh == 0 ? W1a : (hh == 1 ? W1b : W1c);
      dst = W1T + (size_t)hh * 512 * 1024; K = 1024; N = 512;
    }
    const int ntn = N >> 6;
    const int kb = (tau / ntn) * 64, nb = (tau % ntn) * 64;
    const int tx = t & 15, ty = t >> 4;
#pragma unroll
    for (int i = 0; i < 4; i++) {
      float4 v = *(const float4*)&src[(size_t)(kb + ty + 16 * i) * N + nb + tx * 4];
      tile[ty + 16 * i][tx * 4 + 0] = v.x;
      tile[ty + 16 * i][tx * 4 + 1] = v.y;
      tile[ty + 16 * i][tx * 4 + 2] = v.z;
      tile[ty + 16 * i][tx * 4 + 3] = v.w;
    }
    __syncthreads();
    const int wx = t & 7, wy = t >> 3;
#pragma unroll
    for (int i = 0; i < 2; i++) {
      const int n = wy + 32 * i;
      u16x8 o;
#pragma unroll
      for (int j = 0; j < 8; j++) o[j] = f2bf(tile[wx * 8 + j][n]);
      *(u16x8*)&dst[(size_t)(nb + n) * K + kb + wx * 8] = o;
    }
  } else if (bid < 4901) {
    int j = bid - 4889;
    const float* b0 = (j < 4) ? b0a : (j < 8 ? b0b : b0c);
    b0cat[j * 256 + t] = b0[(j & 3) * 256 + t];
  } else if (bid < 4907) {
    int j = bid - 4901;
    const float* b1 = (j < 2) ? b1a : (j < 4 ? b1b : b1c);
    b1cat[j * 256 + t] = b1[(j & 1) * 256 + t];
  } else if (bid < 4911) {
    int idx = (bid - 4907) * 256 + t;
    b_ne[idx] = (idx < 512) ? b_node[idx] : b_edge[idx - 512];
  } else {
    // per-head W2 pad tiles: [3][128][512], rows >= C zero; b2pad [3][128]
    int e = bid - 4911;                      // 0..767
    int h = e >> 8, blk = e & 255;
    const int C = (h == 0) ? 9 : ((h == 1) ? 3 : 5);
    const float* W2 = (h == 0) ? w2a : ((h == 1) ? w2b : w2c);
    const float* b2 = (h == 0) ? b2a : ((h == 1) ? b2b : b2c);
    int idx = blk * 256 + t;
    int n = idx >> 9, k = idx & 511;
    W2T[(size_t)h * 65536 + idx] = (n < C) ? f2bf(W2[(size_t)k * C + n]) : (unsigned short)0;
    if (blk == 0 && t < 128)
      b2pad[h * 128 + t] = (t < C) ? b2[t] : 0.f;
  }
}

// ---------------- shared GEMM body (m97-family, EXACTLY 32 KB LDS) ----------
// EPI: 0 = +bias -> bf16 ; 1 = e-assembly into ci_e (compact) ;
//      2 = relu(+bias) -> bf16 ; 3 = per-head layer-2 fp32 scatter via rmap
//          (REQUIRES aHeadOff = MROWS*DD for h1 per-head slabs!) ;
//      4 = raw bf16 ; 5 = L0': relu(bias + acc + npair), chunk-XOR LDS stage.
template <int EPI>
__device__ __forceinline__ void gemm_body(
    unsigned short* sm,
    const unsigned short* __restrict__ A, int ldA,
    const unsigned short* __restrict__ BT, int ldB, int K,
    int Ntiles,
    const float* __restrict__ bias,
    unsigned short* __restrict__ outb, int ldo,
    const unsigned short* __restrict__ em,
    const int* __restrict__ Mvp,
    unsigned short* __restrict__ ci,
    int blocksPerHead, long long aHeadOff, long long bHeadOff,
    long long oHeadOff, int biasHeadOff,
    const int2* __restrict__ nodes,
    const unsigned short* __restrict__ nfa,
    const unsigned short* __restrict__ nfb,
    const int* __restrict__ rmap, int bid) {
  char* smc = (char*)sm;
  const int t = threadIdx.x;
  const int l = t & 63, w = t >> 6;
  const int wm = w >> 1, wn = w & 1;

  int head = 0;
  unsigned short* outp = outb;
  if (blocksPerHead > 0) {
    head = bid / blocksPerHead;
    bid -= head * blocksPerHead;
    A += (long long)head * aHeadOff;
    BT += (long long)head * bHeadOff;
    bias += head * biasHeadOff;
    outp = outb + (long long)head * oHeadOff;
  }
  const int tn = bid % Ntiles, tm = bid / Ntiles;

  int Mv = MROWS;
  if (Mvp) {
    Mv = *Mvp;
    if (tm * 128 >= Mv) return;   // compact early-exit (uniform branch)
  }

  const int lrow = l >> 3;
  const int scol = (l & 7) ^ lrow;       // pre-swizzled source chunk
  const unsigned short* Ap = A + (size_t)(tm * 128 + w * 8 + lrow) * ldA + scol * 8;
  const unsigned short* Bp = BT + (size_t)(tn * 128 + w * 8 + lrow) * ldB + scol * 8;

  f32x4 acc[4][4] = {};
  const int hi = l >> 4, l15 = l & 15, l7 = l & 7;
  const int nk = K >> 6;

  for (int kt = 0; kt < nk; ++kt) {
#pragma unroll
    for (int c = 0; c < 4; ++c) {
      gll16(Ap + (size_t)c * 32 * ldA, smc + c * 4096 + w * 1024);
      gll16(Bp + (size_t)c * 32 * ldB, smc + 16384 + c * 4096 + w * 1024);
    }
    __syncthreads();
#pragma unroll
    for (int kk = 0; kk < 2; ++kk) {
      const int cb = (((kk << 2) + hi) ^ l7) << 4;
      s16x8 af[4], bfr[4];
#pragma unroll
      for (int m = 0; m < 4; m++)
        af[m] = *(const s16x8*)(smc + (wm * 64 + m * 16 + l15) * 128 + cb);
#pragma unroll
      for (int n = 0; n < 4; n++)
        bfr[n] = *(const s16x8*)(smc + 16384 + (wn * 64 + n * 16 + l15) * 128 + cb);
#pragma unroll
      for (int m = 0; m < 4; m++)
#pragma unroll
        for (int n = 0; n < 4; n++)
          asm volatile("v_mfma_f32_16x16x32_bf16 %0, %1, %2, %0"
                       : "+v"(acc[m][n])
                       : "v"(af[m]), "v"(bfr[n]));
    }
    __syncthreads();
    Ap += 64;
    Bp += 64;
  }
  asm volatile("s_nop 7\n\ts_nop 7\n\ts_nop 7" :::);  // MFMA->VALU hazard guard

  if constexpr (EPI == 5) {
    // Stage npair = nfa[i0]+nfb[i1], coalesced 16B/lane; chunk-XOR swizzle.
    const int se_r = t >> 4;
    const int se_ch = t & 15;
#pragma unroll
    for (int it = 0; it < 8; ++it) {
      const int rr = se_r + (it << 4);
      const int2 nn = nodes[tm * 128 + rr];   // pad rows zero-initialized
      union { unsigned short s[8]; unsigned long long q[2]; } ov;
      u16x8 va = *(const u16x8*)&nfa[(size_t)nn.x * 3072 + tn * 128 + se_ch * 8];
      u16x8 vb = *(const u16x8*)&nfb[(size_t)nn.y * 3072 + tn * 128 + se_ch * 8];
#pragma unroll
      for (int j = 0; j < 8; ++j)
        ov.s[j] = f2bf(bf2f(va[j]) + bf2f(vb[j]));
      const int sch = se_ch ^ ((rr >> 2) & 7);
      *(unsigned long long*)(smc + rr * 256 + (sch << 4)) = ov.q[0];
      *(unsigned long long*)(smc + rr * 256 + (sch << 4) + 8) = ov.q[1];
    }
    __syncthreads();
  }

  // C/D layout: col = lane&15, row = (lane>>4)*4 + reg
  const int gr_base = tm * 128 + wm * 64 + (hi << 2);
  const int gc_base = tn * 128 + wn * 64 + l15;
  const int lr_base = wm * 64 + (hi << 2);
  const int lc_base = wn * 64 + l15;

  int Cc = 0; size_t obase = 0;
  if constexpr (EPI == 3) {
    Cc = (head == 0) ? 9 : ((head == 1) ? 3 : 5);
    obase = (head == 0) ? 0 : ((head == 1) ? (size_t)MROWS * 9 : (size_t)MROWS * 12);
  }

#pragma unroll
  for (int n = 0; n < 4; n++) {
    const int gc = gc_base + n * 16;
    const float bv = (EPI == 4) ? 0.f : bias[gc];
#pragma unroll
    for (int m = 0; m < 4; m++) {
#pragma unroll
      for (int i = 0; i < 4; i++) {
        const int gr = gr_base + m * 16 + i;
        float v = acc[m][n][i] + bv;
        if constexpr (EPI == 0 || EPI == 4) {
          outp[(size_t)gr * ldo + gc] = f2bf(v);
        } else if constexpr (EPI == 1) {
          float e = bf2f(em[(size_t)gr * DD + gc]) + 0.5f * v;
          ci[(size_t)gr * DD + gc] = f2bf(e);
        } else if constexpr (EPI == 2) {
          outp[(size_t)gr * ldo + gc] = f2bf(v > 0.f ? v : 0.f);
        } else if constexpr (EPI == 5) {
          const int lr = lr_base + m * 16 + i;
          const int lc = lc_base + n * 16;
          const int rch = (lc >> 3) ^ ((lr >> 2) & 7);
          v += bf2f(*(const unsigned short*)(smc + lr * 256 + (rch << 4) + (lc & 7) * 2));
          outp[(size_t)gr * ldo + gc] = f2bf(v > 0.f ? v : 0.f);
        } else {
          if (gc < Cc && gr < Mv)
            ((float*)outb)[obase + (size_t)rmap[gr] * Cc + gc] = v;
        }
      }
    }
  }
}

// ---- k_gather_nf: compact gather + outc finish + nf GEMM (ONE launch) ------
__global__ __launch_bounds__(256) void k_gather_nf(
    const float* __restrict__ EF, const float* __restrict__ EE,
    const int* __restrict__ pairs, const int* __restrict__ nrels,
    const int* __restrict__ offs,
    unsigned short* __restrict__ efm, unsigned short* __restrict__ emb,
    int2* __restrict__ nodes, int* __restrict__ rmap,
    const float* __restrict__ h1part,
    const float* __restrict__ b1a, const float* __restrict__ b1b,
    const float* __restrict__ b1c,
    const float* __restrict__ w2a, const float* __restrict__ w2b,
    const float* __restrict__ w2c,
    const float* __restrict__ b2a, const float* __restrict__ b2b,
    const float* __restrict__ b2c, float* __restrict__ outc,
    const unsigned short* __restrict__ node_bf,
    const unsigned short* __restrict__ WnT,
    const float* __restrict__ b_node, unsigned short* __restrict__ nf) {
  __shared__ __align__(16) unsigned short sm[16384];
  const int bid = blockIdx.x, t = threadIdx.x;
  if (bid > MROWS) {
    gemm_body<0>(sm, node_bf, 1024, WnT, 1024, 1024, 4, b_node, nf, 512,
                 nullptr, nullptr, nullptr, 0, 0, 0, 0, 0,
                 nullptr, nullptr, nullptr, nullptr, bid - MROWS - 1);
    return;
  }
  if (bid == MROWS) {
    float* red = (float*)sm;
    for (int h = 0; h < 3; ++h) {
      const float* b1 = h == 0 ? b1a : (h == 1 ? b1b : b1c);
      const float* W2 = h == 0 ? w2a : (h == 1 ? w2b : w2c);
      const float* b2 = h == 0 ? b2a : (h == 1 ? b2b : b2c);
      const int C = h == 0 ? 9 : (h == 1 ? 3 : 5);
      const int obase = h == 0 ? 0 : (h == 1 ? 9 : 12);
      if (t < 9) red[t] = 0.f;
      float s0 = b1[t], s1 = b1[t + 256];
#pragma unroll
      for (int cc = 0; cc < 8; ++cc) {
        s0 += h1part[(size_t)(h * 8 + cc) * 512 + t];
        s1 += h1part[(size_t)(h * 8 + cc) * 512 + t + 256];
      }
      const float hv0 = fmaxf(s0, 0.f), hv1 = fmaxf(s1, 0.f);
      __syncthreads();
      float p[9] = {0.f, 0.f, 0.f, 0.f, 0.f, 0.f, 0.f, 0.f, 0.f};
#pragma unroll
      for (int c = 0; c < 9; ++c)
        if (c < C) p[c] = hv0 * W2[(size_t)t * C + c] + hv1 * W2[(size_t)(t + 256) * C + c];
#pragma unroll
      for (int c = 0; c < 9; ++c)
#pragma unroll
        for (int off = 32; off; off >>= 1) p[c] += __shfl_xor(p[c], off);
      if ((t & 63) == 0)
        for (int c = 0; c < C; ++c) atomicAdd(&red[c], p[c]);
      __syncthreads();
      if (t < C) outc[obase + t] = red[t] + b2[t];
      __syncthreads();
    }
    return;
  }
  int r = bid;
  int b = r / PP, p = r - b * PP;
  if (p >= nrels[b]) return;
  const int cr = offs[b] + p;
  int i0 = pairs[r * 2 + 0], i1 = pairs[r * 2 + 1];
  if (t == 0) {
    nodes[cr] = make_int2(b * NNODE + i0, b * NNODE + i1);
    rmap[cr] = r;
  }
  const float4* e01 = (const float4*)(EF + ((size_t)((b * NNODE + i0) * NNODE + i1)) * DEF);
  const float4* e10 = (const float4*)(EF + ((size_t)((b * NNODE + i1) * NNODE + i0)) * DEF);
  float4 a = e01[t], c = e10[t];
  ushort4 o;
  o.x = f2bf(0.5f * (a.x + c.x));
  o.y = f2bf(0.5f * (a.y + c.y));
  o.z = f2bf(0.5f * (a.z + c.z));
  o.w = f2bf(0.5f * (a.w + c.w));
  ((ushort4*)(efm + (size_t)cr * DEF))[t] = o;
  const float2* g01 = (const float2*)(EE + ((size_t)((b * NNODE + i0) * NNODE + i1)) * DD);
  const float2* g10 = (const float2*)(EE + ((size_t)((b * NNODE + i1) * NNODE + i0)) * DD);
  float2 x = g01[t], y = g10[t];
  ushort2 eo;
  eo.x = f2bf(0.25f * (x.x + y.x));
  eo.y = f2bf(0.25f * (x.y + y.y));
  ((ushort2*)(emb + (size_t)cr * DD))[t] = eo;
}

// ---- k_mid: e-GEMM + nfa/nfb GEMM + fillout (ONE launch) --------------------
__global__ __launch_bounds__(256) void k_mid(
    const unsigned short* __restrict__ efm, const unsigned short* __restrict__ WeT,
    const float* __restrict__ b_edge,
    const unsigned short* __restrict__ EMb, const int* __restrict__ Mvp,
    unsigned short* __restrict__ ci_e,
    const unsigned short* __restrict__ nf, const unsigned short* __restrict__ W0T,
    unsigned short* __restrict__ nfa,
    const float* __restrict__ outc, float* __restrict__ out) {
  __shared__ __align__(16) unsigned short sm[16384];
  const int bid = blockIdx.x, t = threadIdx.x;
  if (bid < 528) {
    gemm_body<1>(sm, efm, 1024, WeT, 1024, 1024, 4, b_edge, nullptr, 0,
                 EMb, Mvp, ci_e, 0, 0, 0, 0, 0,
                 nullptr, nullptr, nullptr, nullptr, bid);
  } else if (bid < 1680) {
    gemm_body<4>(sm, nf, 512, W0T, 1536, 512, 24, nullptr, nfa, 3072,
                 nullptr, nullptr, nullptr, 576,
                 0, 512, (long long)MNODE * 3072, 0,
                 nullptr, nullptr, nullptr, nullptr, bid - 528);
  } else {
    const int e = (bid - 1680) * 256 + t;
    if (e < MROWS * 17) {
      int c;
      if (e < MROWS * 9) c = e % 9;
      else if (e < MROWS * 12) c = 9 + (e - MROWS * 9) % 3;
      else c = 12 + (e - MROWS * 12) % 5;
      out[e] = outc[c];
    }
  }
}

// ---------------- plain GEMM wrapper (L0', L1, L2) ---------------------------
template <int EPI>
__global__ __launch_bounds__(256) void k_gemm(
    const unsigned short* __restrict__ A, int ldA,
    const unsigned short* __restrict__ BT, int ldB, int K,
    int Ntiles,
    const float* __restrict__ bias,
    unsigned short* __restrict__ outb, int ldo,
    const unsigned short* __restrict__ em,
    const int* __restrict__ Mvp,
    unsigned short* __restrict__ ci,
    int blocksPerHead, long long aHeadOff, long long bHeadOff,
    long long oHeadOff, int biasHeadOff,
    const int2* __restrict__ nodes,
    const unsigned short* __restrict__ nfa,
    const unsigned short* __restrict__ nfb,
    const int* __restrict__ rmap) {
  __shared__ __align__(16) unsigned short sm[16384];
  gemm_body<EPI>(sm, A, ldA, BT, ldB, K, Ntiles, bias, outb, ldo, em, Mvp, ci,
                 blocksPerHead, aHeadOff, bHeadOff, oHeadOff, biasHeadOff,
                 nodes, nfa, nfb, rmap, blockIdx.x);
}

// ---------------- launcher ----------------
extern "C" void kernel_launch(void* const* d_in, const int* in_sizes, int n_in,
                              void* d_out, int out_size, void* d_ws, size_t ws_size,
                              hipStream_t stream) {
  const float* node   = (const float*)d_in[0];
  const float* EF     = (const float*)d_in[1];
  const float* EE     = (const float*)d_in[2];
  const int*   pairs  = (const int*)d_in[3];
  const int*   nrels  = (const int*)d_in[4];
  const float* W_node = (const float*)d_in[5];
  const float* b_node = (const float*)d_in[6];
  const float* W_edge = (const float*)d_in[7];
  const float* b_edge = (const float*)d_in[8];
  const float* hW0[3] = {(const float*)d_in[9],  (const float*)d_in[15], (const float*)d_in[21]};
  const float* hb0[3] = {(const float*)d_in[10], (const float*)d_in[16], (const float*)d_in[22]};
  const float* hW1[3] = {(const float*)d_in[11], (const float*)d_in[17], (const float*)d_in[23]};
  const float* hb1[3] = {(const float*)d_in[12], (const float*)d_in[18], (const float*)d_in[24]};
  const float* hW2[3] = {(const float*)d_in[13], (const float*)d_in[19], (const float*)d_in[25]};
  const float* hb2[3] = {(const float*)d_in[14], (const float*)d_in[20], (const float*)d_in[26]};

  char* ws = (char*)d_ws;
  size_t off = 0;
  auto alloc = [&](size_t bytes) {
    char* p = ws + off;
    off += (bytes + 255) & ~(size_t)255;
    return p;
  };
  // --- persistent front ---
  unsigned short* WnT    = (unsigned short*)alloc((size_t)512 * 1024 * 2);
  unsigned short* WeT    = (unsigned short*)alloc((size_t)512 * 1024 * 2);
  unsigned short* W0T    = (unsigned short*)alloc((size_t)3072 * 1536 * 2);
  unsigned short* W1T    = (unsigned short*)alloc((size_t)3 * 512 * 1024 * 2);
  unsigned short* W2T    = (unsigned short*)alloc((size_t)3 * 128 * 512 * 2);
  float*          b2pad  = (float*)alloc((size_t)3 * 128 * 4);
  float*          b0cat  = (float*)alloc((size_t)3072 * 4);
  float*          b1cat  = (float*)alloc((size_t)1536 * 4);
  float*          b_ne   = (float*)alloc((size_t)1024 * 4);
  int2*           nodes  = (int2*)alloc((size_t)MROWS * 8);
  int*            offs   = (int*)alloc((size_t)256 * 4);
  int*            Mv     = (int*)alloc(256);
  int*            rmap   = (int*)alloc((size_t)MROWS * 4);
  float*          outc   = (float*)alloc((size_t)32 * 4);
  float*          h1part = (float*)alloc((size_t)24 * 512 * 4);
  // --- zone B: [ci_e | nfa | nfb] (55.1 MB), disjoint from efm/EMb.
  //     Dead after L0' -> h1 (51.9 MB) overlays zone B.
  size_t zoneB = off;
  unsigned short* ci_e = (unsigned short*)alloc((size_t)MROWS * DD * 2);
  unsigned short* nfa  = (unsigned short*)alloc((size_t)MNODE * 3072 * 2);
  unsigned short* nfb  = (unsigned short*)alloc((size_t)MNODE * 3072 * 2);
  // --- zone C: [node_bf | nf | efm | EMb], dead after k_mid -> h0big overlays.
  size_t zoneC = off;
  unsigned short* node_bf = (unsigned short*)alloc((size_t)MNODE * DNF * 2);
  unsigned short* nf      = (unsigned short*)alloc((size_t)MNODE * DD * 2);
  unsigned short* efm     = (unsigned short*)alloc((size_t)MROWS * DEF * 2);
  unsigned short* EMb     = (unsigned short*)alloc((size_t)MROWS * DD * 2);
  // overlays
  unsigned short* h1    = (unsigned short*)(ws + zoneB);
  unsigned short* h0big = (unsigned short*)(ws + zoneC);

  // 1. front: h1c partials + scan + conv + transposes + pads + W2 tiles
  k_front<<<5679, 256, 0, stream>>>(nrels, offs, Mv, nodes, h1part,
      node, node_bf, W_node, WnT, W_edge, WeT,
      hW0[0], hW0[1], hW0[2], W0T, hW1[0], hW1[1], hW1[2], W1T,
      hW2[0], hW2[1], hW2[2], hb2[0], hb2[1], hb2[2], W2T, b2pad,
      hb0[0], hb0[1], hb0[2], b0cat, hb1[0], hb1[1], hb1[2], b1cat,
      b_node, b_edge, b_ne);

  // 2. gather + finish + nf GEMM
  k_gather_nf<<<MROWS + 1 + (MNODE / 128) * 4, 256, 0, stream>>>(
      EF, EE, pairs, nrels, offs, efm, EMb, nodes, rmap, h1part,
      hb1[0], hb1[1], hb1[2], hW2[0], hW2[1], hW2[2],
      hb2[0], hb2[1], hb2[2], outc,
      node_bf, WnT, b_ne, nf);

  // 3. mid: e-GEMM + nfa/nfb + fillout
  k_mid<<<1680 + (MROWS * 17 + 255) / 256, 256, 0, stream>>>(
      efm, WeT, b_ne + 512, EMb, Mv, ci_e,
      nf, W0T, nfa, outc, (float*)d_out);

  // 4. L0' (compact): h0 = relu(ci_e @ W0[1024:1536,:]^T + b0 + npair)
  k_gemm<5><<<MTILES * 24, 256, 0, stream>>>(
      ci_e, 512, W0T + 1024, 1536, 512, 24, b0cat, h0big, 3072,
      nullptr, Mv, nullptr, 0, 0, 0, 0, 0, nodes, nfa, nfb, nullptr);

  // 5. L1 (compact, fused over heads) -> h1[h] dense [MROWS][512]
  k_gemm<2><<<3 * MTILES * 4, 256, 0, stream>>>(
      h0big, 3072, W1T, 1024, 1024, 4, b1cat, h1, 512,
      nullptr, Mv, nullptr, MTILES * 4,
      1024, (long long)512 * 1024, (long long)MROWS * DD, 512,
      nullptr, nullptr, nullptr, nullptr);

  // 6. L2 (per-head padded GEMM, 396 blocks): scatter into pre-filled d_out.
  //    aHeadOff = MROWS*DD (h1 per-head slab) -- r19's bug was 0 here.
  k_gemm<3><<<3 * MTILES, 256, 0, stream>>>(
      h1, 512, W2T, 512, 512, 1, b2pad, (unsigned short*)d_out, 0,
      nullptr, Mv, nullptr, MTILES,
      (long long)MROWS * DD, (long long)128 * 512, 0, 128,
      nullptr, nullptr, nullptr, rmap);
}